// Round 7
// baseline (135.635 us; speedup 1.0000x reference)
//
#include <hip/hip_runtime.h>

typedef _Float16 f16;
typedef _Float16 f16x8 __attribute__((ext_vector_type(8)));
typedef _Float16 f16x4 __attribute__((ext_vector_type(4)));
typedef _Float16 f16x2 __attribute__((ext_vector_type(2)));
typedef float f32x4 __attribute__((ext_vector_type(4)));
typedef float f32x16 __attribute__((ext_vector_type(16)));

#define MDIM 128
#define NDIM 256
#define CDIM 256
#define ROWS (MDIM*NDIM)   // 32768
#define L2E 1.4426950408889634f

__device__ inline int pk2(float a, float b) {
  union { f16x2 h; int i; } u;
  u.h[0] = (f16)a; u.h[1] = (f16)b;
  return u.i;
}

// ---------------- K0: weight prepack (LDS-transpose tiles) ----------------
// wq/wk/wv -> f16 [je][k], je=h*32+c (orig col j=(je&31)*8+(je>>5)); 1/sqrt(32)
// folded into wq. wf -> f16 [col][ke], ke row-permuted the same way.
__global__ __launch_bounds__(256) void k_prep(
    const float* __restrict__ wq, const float* __restrict__ wk,
    const float* __restrict__ wv, const float* __restrict__ wf,
    f16* __restrict__ bq, f16* __restrict__ bk, f16* __restrict__ bv,
    f16* __restrict__ bw)
{
  __shared__ f16 ld[64][264];
  int which = blockIdx.x >> 2, kb = blockIdx.x & 3;
  int t = threadIdx.x;
  int k0 = kb * 64;
  if (which < 3) {
    const float* W = which == 0 ? wq : which == 1 ? wk : wv;
    f16* dst       = which == 0 ? bq : which == 1 ? bk : bv;
    float sc = which == 0 ? 0.17677669529663689f : 1.0f;
    for (int r = 0; r < 64; ++r)
      ld[r][t] = (f16)(W[(size_t)(k0 + r) * 256 + t] * sc);
    __syncthreads();
    int j = (t & 31) * 8 + (t >> 5);
#pragma unroll
    for (int rr = 0; rr < 8; ++rr) {
      f16x8 o;
#pragma unroll
      for (int i = 0; i < 8; ++i) o[i] = ld[rr * 8 + i][j];
      *(f16x8*)(dst + (size_t)t * 256 + k0 + rr * 8) = o;
    }
  } else {
    for (int r = 0; r < 64; ++r) {
      int ke = k0 + r;
      int jr = (ke & 31) * 8 + (ke >> 5);
      ld[r][t] = (f16)wf[(size_t)jr * 256 + t];
    }
    __syncthreads();
#pragma unroll
    for (int rr = 0; rr < 8; ++rr) {
      f16x8 o;
#pragma unroll
      for (int i = 0; i < 8; ++i) o[i] = ld[rr * 8 + i][t];
      *(f16x8*)(bw + (size_t)t * 256 + k0 + rr * 8) = o;
    }
  }
}

// ---------------- K1: LayerNorm -> fp16 (wave per row) ----------------
__global__ __launch_bounds__(256) void k_ln(const float* __restrict__ x,
                                            const float* __restrict__ g,
                                            const float* __restrict__ b,
                                            f16* __restrict__ y)
{
  int row  = blockIdx.x * 4 + (threadIdx.x >> 6);
  int lane = threadIdx.x & 63;
  const float4 xv = *(const float4*)(x + (size_t)row * CDIM + lane * 4);
  float s  = xv.x + xv.y + xv.z + xv.w;
  float s2 = xv.x*xv.x + xv.y*xv.y + xv.z*xv.z + xv.w*xv.w;
#pragma unroll
  for (int m = 1; m < 64; m <<= 1) {
    s  += __shfl_xor(s,  m, 64);
    s2 += __shfl_xor(s2, m, 64);
  }
  float mu  = s * (1.0f / CDIM);
  float var = s2 * (1.0f / CDIM) - mu * mu;
  float rs  = rsqrtf(var + 1e-5f);
  const float4 gv = *(const float4*)(g + lane * 4);
  const float4 bv = *(const float4*)(b + lane * 4);
  f16x4 o;
  o[0] = (f16)((xv.x - mu) * rs * gv.x + bv.x);
  o[1] = (f16)((xv.y - mu) * rs * gv.y + bv.y);
  o[2] = (f16)((xv.z - mu) * rs * gv.z + bv.z);
  o[3] = (f16)((xv.w - mu) * rs * gv.w + bv.w);
  *(f16x4*)(y + (size_t)row * CDIM + lane * 4) = o;
}

// ---------------- K2: QKV GEMM — LDS-free, barrier-free ----------------
// grid (256 row-tiles x 6 col-tiles), 256 thr / 4 waves (2x2), wave = 64x64.
// A- and B-fragments load directly from L2/L3 (both stored in MFMA fragment
// layout [row][k] / [col][k]). V section transposes via wave-private LDS.
__global__ __launch_bounds__(256, 4) void k_qkv(const f16* __restrict__ xh,
    const f16* __restrict__ bq, const f16* __restrict__ bk, const f16* __restrict__ bv,
    f16* __restrict__ qo, f16* __restrict__ ko, f16* __restrict__ vT)
{
  __shared__ f16 vtmp[4][16][72];
  int bm = blockIdx.x;          // 128-row tile
  int ct = blockIdx.y;          // 128-col tile (0..5)
  int t = threadIdx.x, lane = t & 63, w = t >> 6;
  int wr = w >> 1, wc = w & 1;
  int l15 = lane & 15, l4 = lane >> 4;
  int r0  = bm * 128 + wr * 64;
  int gc0 = ct * 128 + wc * 64;
  int sec = gc0 >> 8;
  const f16* B = sec == 0 ? bq : sec == 1 ? bk : bv;
  int c0 = gc0 & 255;
  f32x4 acc[4][4] = {};
#pragma unroll
  for (int kt = 0; kt < 8; ++kt) {
    f16x8 af[4], bf[4];
#pragma unroll
    for (int mi = 0; mi < 4; ++mi)
      af[mi] = *(const f16x8*)(xh + (size_t)(r0 + mi * 16 + l15) * 256 + kt * 32 + l4 * 8);
#pragma unroll
    for (int ni = 0; ni < 4; ++ni)
      bf[ni] = *(const f16x8*)(B + (size_t)(c0 + ni * 16 + l15) * 256 + kt * 32 + l4 * 8);
#pragma unroll
    for (int mi = 0; mi < 4; ++mi)
#pragma unroll
      for (int ni = 0; ni < 4; ++ni)
        acc[mi][ni] = __builtin_amdgcn_mfma_f32_16x16x32_f16(af[mi], bf[ni], acc[mi][ni], 0, 0, 0);
  }
  if (sec < 2) {
    f16* dst = sec == 0 ? qo : ko;
#pragma unroll
    for (int mi = 0; mi < 4; ++mi)
#pragma unroll
      for (int ni = 0; ni < 4; ++ni)
#pragma unroll
        for (int r = 0; r < 4; ++r)
          dst[(size_t)(r0 + mi * 16 + l4 * 4 + r) * 256 + c0 + ni * 16 + l15] = (f16)acc[mi][ni][r];
  } else {
    // V: rows are (m, n); write transposed vT[m][ch][n] via wave-private LDS
    int m = bm >> 1, n0 = (bm & 1) * 128 + wr * 64;
    int ch = lane >> 2, nq = (lane & 3) * 16;
#pragma unroll
    for (int ni = 0; ni < 4; ++ni) {
#pragma unroll
      for (int mi = 0; mi < 4; ++mi)
#pragma unroll
        for (int r = 0; r < 4; ++r)
          vtmp[w][l15][mi * 16 + l4 * 4 + r] = (f16)acc[mi][ni][r];
      f16x8 v0 = *(const f16x8*)&vtmp[w][ch][nq];
      f16x8 v1 = *(const f16x8*)&vtmp[w][ch][nq + 8];
      size_t gdst = ((size_t)m * 256 + c0 + ni * 16 + ch) * 256 + n0 + nq;
      *(f16x8*)(vT + gdst)     = v0;
      *(f16x8*)(vT + gdst + 8) = v1;
    }
  }
}

// ---------------- K3: attention (block = (m,h), 8 waves x 32 queries) ------
__global__ __launch_bounds__(512, 4) void k_attn(const f16* __restrict__ q,
    const f16* __restrict__ k, const f16* __restrict__ vT, f16* __restrict__ o)
{
  __shared__ f16 ks[256][40];
  __shared__ f16 vt[32][264];
  int bx = blockIdx.x;
  int m = bx >> 3, h = bx & 7;
  int t = threadIdx.x, lane = t & 63, w = t >> 6;
  int i32 = lane & 31, hi = lane >> 5;
  size_t rowbase = (size_t)m * 256;
#pragma unroll
  for (int p = 0; p < 2; ++p) {
    int n = p * 128 + (t >> 2);
    int c0 = (t & 3) * 8;
    *(f16x8*)&ks[n][c0] = *(const f16x8*)(k + (rowbase + n) * 256 + h * 32 + c0);
  }
#pragma unroll
  for (int p = 0; p < 2; ++p) {
    int idx = p * 512 + t;
    int c = idx >> 5, nb = (idx & 31) * 8;
    *(f16x8*)&vt[c][nb] = *(const f16x8*)(vT + ((size_t)m * 256 + h * 32 + c) * 256 + nb);
  }
  __syncthreads();
  int qi0 = w * 32;
  const f16* qp = q + (rowbase + qi0 + i32) * 256 + h * 32 + hi * 8;
  f16x8 qf0 = *(const f16x8*)(qp);
  f16x8 qf1 = *(const f16x8*)(qp + 16);
  f32x16 O = {};
  float m_run = -1e30f, l_run = 0.f;
#pragma unroll 2
  for (int kb = 0; kb < 8; ++kb) {
    f16x8 kf0 = *(const f16x8*)&ks[kb * 32 + i32][hi * 8];
    f16x8 kf1 = *(const f16x8*)&ks[kb * 32 + i32][16 + hi * 8];
    f32x16 s = {};
    __builtin_amdgcn_s_setprio(1);
    s = __builtin_amdgcn_mfma_f32_32x32x16_f16(kf0, qf0, s, 0, 0, 0);
    s = __builtin_amdgcn_mfma_f32_32x32x16_f16(kf1, qf1, s, 0, 0, 0);
    __builtin_amdgcn_s_setprio(0);
#pragma unroll
    for (int r = 0; r < 16; ++r) s[r] *= L2E;
    float pmax = s[0];
#pragma unroll
    for (int r = 1; r < 16; ++r) pmax = fmaxf(pmax, s[r]);
    pmax = fmaxf(pmax, __shfl_xor(pmax, 32, 64));
    if (!__all(pmax - m_run <= 8.f)) {
      float m_new = fmaxf(m_run, pmax);
      float f = __builtin_amdgcn_exp2f(m_run - m_new);
      l_run *= f;
#pragma unroll
      for (int r = 0; r < 16; ++r)
        O[r] *= __shfl(f, (r & 3) + 8 * (r >> 2) + 4 * hi, 64);
      m_run = m_new;
    }
    float lsum = 0.f;
#pragma unroll
    for (int r = 0; r < 16; ++r) {
      float e = __builtin_amdgcn_exp2f(s[r] - m_run);
      s[r] = e;
      lsum += e;
    }
    lsum += __shfl_xor(lsum, 32, 64);
    l_run += lsum;
    int W0[4], W1[4];
#pragma unroll
    for (int qq = 0; qq < 4; ++qq) {
      W0[qq] = pk2(s[4 * qq],     s[4 * qq + 1]);
      W1[qq] = pk2(s[4 * qq + 2], s[4 * qq + 3]);
    }
#pragma unroll
    for (int ks2 = 0; ks2 < 2; ++ks2) {
      int X0 = W0[2 * ks2], Y0 = W0[2 * ks2 + 1];
      int X1 = W1[2 * ks2], Y1 = W1[2 * ks2 + 1];
      int a0 = __shfl(X0, i32, 64),      b0 = __shfl(Y0, i32, 64);
      int a1 = __shfl(X1, i32, 64),      b1 = __shfl(Y1, i32, 64);
      int a2 = __shfl(X0, i32 + 32, 64), b2 = __shfl(Y0, i32 + 32, 64);
      int a3 = __shfl(X1, i32 + 32, 64), b3 = __shfl(Y1, i32 + 32, 64);
      union { unsigned int ww[4]; f16x8 v; } pa;
      pa.ww[0] = hi ? (unsigned)b0 : (unsigned)a0;
      pa.ww[1] = hi ? (unsigned)b1 : (unsigned)a1;
      pa.ww[2] = hi ? (unsigned)b2 : (unsigned)a2;
      pa.ww[3] = hi ? (unsigned)b3 : (unsigned)a3;
      f16x8 vb = *(const f16x8*)&vt[i32][kb * 32 + ks2 * 16 + hi * 8];
      __builtin_amdgcn_s_setprio(1);
      O = __builtin_amdgcn_mfma_f32_32x32x16_f16(pa.v, vb, O, 0, 0, 0);
      __builtin_amdgcn_s_setprio(0);
    }
  }
  float inv = 1.f / l_run;
#pragma unroll
  for (int r = 0; r < 16; ++r) {
    int i = (r & 3) + 8 * (r >> 2) + 4 * hi;
    float fr = __shfl(inv, i, 64);
    o[(rowbase + (size_t)(qi0 + i)) * 256 + h * 32 + i32] = (f16)(O[r] * fr);
  }
}

// ---------------- K4: output projection — LDS-free, barrier-free ----------
// grid (512 row-tiles x 4 col-tiles), 256 thr / 4 waves (2x2), wave = 32x32.
__global__ __launch_bounds__(256, 4) void k_out(const f16* __restrict__ a,
    const f16* __restrict__ bw, const float* __restrict__ bias,
    float* __restrict__ out)
{
  int bm = blockIdx.x;
  int ct = blockIdx.y;
  int t = threadIdx.x, lane = t & 63, w = t >> 6;
  int wr = w >> 1, wc = w & 1;
  int l15 = lane & 15, l4 = lane >> 4;
  int r0 = bm * 64 + wr * 32;
  int c0 = ct * 64 + wc * 32;
  f32x4 acc[2][2] = {};
#pragma unroll
  for (int kt = 0; kt < 8; ++kt) {
    f16x8 af[2], bf[2];
#pragma unroll
    for (int mi = 0; mi < 2; ++mi)
      af[mi] = *(const f16x8*)(a + (size_t)(r0 + mi * 16 + l15) * 256 + kt * 32 + l4 * 8);
#pragma unroll
    for (int ni = 0; ni < 2; ++ni)
      bf[ni] = *(const f16x8*)(bw + (size_t)(c0 + ni * 16 + l15) * 256 + kt * 32 + l4 * 8);
#pragma unroll
    for (int mi = 0; mi < 2; ++mi)
#pragma unroll
      for (int ni = 0; ni < 2; ++ni)
        acc[mi][ni] = __builtin_amdgcn_mfma_f32_16x16x32_f16(af[mi], bf[ni], acc[mi][ni], 0, 0, 0);
  }
  float b0 = bias[c0 + l15], b1 = bias[c0 + 16 + l15];
#pragma unroll
  for (int mi = 0; mi < 2; ++mi)
#pragma unroll
    for (int r = 0; r < 4; ++r) {
      int row = r0 + mi * 16 + l4 * 4 + r;
      out[(size_t)row * 256 + c0 + l15]      = acc[mi][0][r] + b0;
      out[(size_t)row * 256 + c0 + 16 + l15] = acc[mi][1][r] + b1;
    }
}

extern "C" void kernel_launch(void* const* d_in, const int* in_sizes, int n_in,
                              void* d_out, int out_size, void* d_ws, size_t ws_size,
                              hipStream_t stream)
{
  const float* x  = (const float*)d_in[0];
  const float* g  = (const float*)d_in[1];
  const float* b  = (const float*)d_in[2];
  const float* wq = (const float*)d_in[3];
  const float* wk = (const float*)d_in[4];
  const float* wv = (const float*)d_in[5];
  const float* wf = (const float*)d_in[6];
  const float* bf = (const float*)d_in[7];
  float* out = (float*)d_out;

  char* ws = (char*)d_ws;
  f16* xh  = (f16*)(ws);                                 // LN output
  f16* qh  = (f16*)(ws + (size_t)16 * 1024 * 1024);
  f16* kh  = (f16*)(ws + (size_t)32 * 1024 * 1024);
  f16* vTh = (f16*)(ws + (size_t)48 * 1024 * 1024);      // [m][ch][n]
  char* wbase = ws + (size_t)64 * 1024 * 1024;
  f16* bq = (f16*)(wbase);
  f16* bk = (f16*)(wbase + 128 * 1024);
  f16* bv = (f16*)(wbase + 256 * 1024);
  f16* bw = (f16*)(wbase + 384 * 1024);
  f16* ah = (f16*)(ws + (size_t)80 * 1024 * 1024);       // attn output

  k_prep<<<16,                256, 0, stream>>>(wq, wk, wv, wf, bq, bk, bv, bw);
  k_ln  <<<ROWS / 4,          256, 0, stream>>>(x, g, b, xh);
  k_qkv <<<dim3(256, 6),      256, 0, stream>>>(xh, bq, bk, bv, qh, kh, vTh);
  k_attn<<<1024,              512, 0, stream>>>(qh, kh, vTh, ah);
  k_out <<<dim3(512, 4),      256, 0, stream>>>(ah, bw, bf, out);
}

// Round 8
// 88.732 us; speedup vs baseline: 1.5286x; 1.5286x over previous
//
#include <hip/hip_runtime.h>

typedef _Float16 f16;
typedef _Float16 f16x8 __attribute__((ext_vector_type(8)));
typedef _Float16 f16x4 __attribute__((ext_vector_type(4)));
typedef _Float16 f16x2 __attribute__((ext_vector_type(2)));
typedef float f32x4 __attribute__((ext_vector_type(4)));
typedef float f32x16 __attribute__((ext_vector_type(16)));

#define MDIM 128
#define NDIM 256
#define CDIM 256
#define ROWS (MDIM*NDIM)   // 32768
#define L2E 1.4426950408889634f

__device__ inline int pk2(float a, float b) {
  union { f16x2 h; int i; } u;
  u.h[0] = (f16)a; u.h[1] = (f16)b;
  return u.i;
}

// ---------------- K0: weight prepack (LDS-transpose tiles) ----------------
// wq/wk/wv -> f16 [je][k], je=h*32+c (orig col j=(je&31)*8+(je>>5)); 1/sqrt(32)
// folded into wq. wf -> f16 [col][ke], ke row-permuted the same way.
__global__ __launch_bounds__(256) void k_prep(
    const float* __restrict__ wq, const float* __restrict__ wk,
    const float* __restrict__ wv, const float* __restrict__ wf,
    f16* __restrict__ bq, f16* __restrict__ bk, f16* __restrict__ bv,
    f16* __restrict__ bw)
{
  __shared__ f16 ld[64][264];
  int which = blockIdx.x >> 2, kb = blockIdx.x & 3;
  int t = threadIdx.x;
  int k0 = kb * 64;
  if (which < 3) {
    const float* W = which == 0 ? wq : which == 1 ? wk : wv;
    f16* dst       = which == 0 ? bq : which == 1 ? bk : bv;
    float sc = which == 0 ? 0.17677669529663689f : 1.0f;
    for (int r = 0; r < 64; ++r)
      ld[r][t] = (f16)(W[(size_t)(k0 + r) * 256 + t] * sc);
    __syncthreads();
    int j = (t & 31) * 8 + (t >> 5);
#pragma unroll
    for (int rr = 0; rr < 8; ++rr) {
      f16x8 o;
#pragma unroll
      for (int i = 0; i < 8; ++i) o[i] = ld[rr * 8 + i][j];
      *(f16x8*)(dst + (size_t)t * 256 + k0 + rr * 8) = o;
    }
  } else {
    for (int r = 0; r < 64; ++r) {
      int ke = k0 + r;
      int jr = (ke & 31) * 8 + (ke >> 5);
      ld[r][t] = (f16)wf[(size_t)jr * 256 + t];
    }
    __syncthreads();
#pragma unroll
    for (int rr = 0; rr < 8; ++rr) {
      f16x8 o;
#pragma unroll
      for (int i = 0; i < 8; ++i) o[i] = ld[rr * 8 + i][t];
      *(f16x8*)(bw + (size_t)t * 256 + k0 + rr * 8) = o;
    }
  }
}

// ---------------- K1: LayerNorm -> fp16 (wave per row) ----------------
__global__ __launch_bounds__(256) void k_ln(const float* __restrict__ x,
                                            const float* __restrict__ g,
                                            const float* __restrict__ b,
                                            f16* __restrict__ y)
{
  int row  = blockIdx.x * 4 + (threadIdx.x >> 6);
  int lane = threadIdx.x & 63;
  const float4 xv = *(const float4*)(x + (size_t)row * CDIM + lane * 4);
  float s  = xv.x + xv.y + xv.z + xv.w;
  float s2 = xv.x*xv.x + xv.y*xv.y + xv.z*xv.z + xv.w*xv.w;
#pragma unroll
  for (int m = 1; m < 64; m <<= 1) {
    s  += __shfl_xor(s,  m, 64);
    s2 += __shfl_xor(s2, m, 64);
  }
  float mu  = s * (1.0f / CDIM);
  float var = s2 * (1.0f / CDIM) - mu * mu;
  float rs  = rsqrtf(var + 1e-5f);
  const float4 gv = *(const float4*)(g + lane * 4);
  const float4 bv = *(const float4*)(b + lane * 4);
  f16x4 o;
  o[0] = (f16)((xv.x - mu) * rs * gv.x + bv.x);
  o[1] = (f16)((xv.y - mu) * rs * gv.y + bv.y);
  o[2] = (f16)((xv.z - mu) * rs * gv.z + bv.z);
  o[3] = (f16)((xv.w - mu) * rs * gv.w + bv.w);
  *(f16x4*)(y + (size_t)row * CDIM + lane * 4) = o;
}

// ---------------- K2: QKV GEMM — A in registers, B LDS-staged -------------
// grid (512 row-tiles, 3 matrices), 256 thr / 4 waves, wave = 16 rows.
// A-frags (8 x f16x8 = 32 VGPR) loaded ONCE up-front, fully pipelined.
// Then 4 col-tiles of 64: stage Bs (33.8 KB), 2 barriers/tile.
// sec==2 (V) transposes through block-wide vtmp to vT[m][ch][n].
__global__ __launch_bounds__(256, 4) void k_qkv(const f16* __restrict__ xh,
    const f16* __restrict__ bq, const f16* __restrict__ bk, const f16* __restrict__ bv,
    f16* __restrict__ qo, f16* __restrict__ ko, f16* __restrict__ vT)
{
  __shared__ f16 Bs[64][264];
  __shared__ f16 vtmp[64][72];
  int bm = blockIdx.x;          // 64-row tile
  int sec = blockIdx.y;         // 0=q, 1=k, 2=v
  const f16* B = sec == 0 ? bq : sec == 1 ? bk : bv;
  int t = threadIdx.x, lane = t & 63, w = t >> 6;
  int l15 = lane & 15, l4 = lane >> 4;
  int r0 = bm * 64 + w * 16;
  int pr = t >> 2, pc = (t & 3) * 8;
  // A-fragments: one-time, independent loads
  f16x8 af[8];
#pragma unroll
  for (int kt = 0; kt < 8; ++kt)
    af[kt] = *(const f16x8*)(xh + (size_t)(r0 + l15) * 256 + kt * 32 + l4 * 8);
  for (int ct = 0; ct < 4; ++ct) {
#pragma unroll
    for (int p = 0; p < 8; ++p)
      *(f16x8*)&Bs[pr][pc + p * 32] =
        *(const f16x8*)(B + (size_t)(ct * 64 + pr) * 256 + pc + p * 32);
    __syncthreads();
    f32x4 acc[4] = {};
#pragma unroll
    for (int kt = 0; kt < 8; ++kt) {
#pragma unroll
      for (int ni = 0; ni < 4; ++ni) {
        f16x8 bf = *(const f16x8*)&Bs[ni * 16 + l15][kt * 32 + l4 * 8];
        acc[ni] = __builtin_amdgcn_mfma_f32_16x16x32_f16(af[kt], bf, acc[ni], 0, 0, 0);
      }
    }
    if (sec < 2) {
      f16* dst = sec == 0 ? qo : ko;
#pragma unroll
      for (int ni = 0; ni < 4; ++ni)
#pragma unroll
        for (int r = 0; r < 4; ++r)
          dst[(size_t)(r0 + l4 * 4 + r) * 256 + ct * 64 + ni * 16 + l15] = (f16)acc[ni][r];
      __syncthreads();   // Bs reads done before restage
    } else {
      // V: block-wide transpose vtmp[ch 64][n 64] -> vT[m][ch][n] coalesced
#pragma unroll
      for (int ni = 0; ni < 4; ++ni)
#pragma unroll
        for (int r = 0; r < 4; ++r)
          vtmp[ni * 16 + l15][w * 16 + l4 * 4 + r] = (f16)acc[ni][r];
      __syncthreads();
      int ch = t >> 2, nq = (t & 3) * 16;
      int m = bm >> 2, n0 = (bm & 3) * 64;
      size_t gd = ((size_t)m * 256 + ct * 64 + ch) * 256 + n0 + nq;
      *(f16x8*)(vT + gd)     = *(const f16x8*)&vtmp[ch][nq];
      *(f16x8*)(vT + gd + 8) = *(const f16x8*)&vtmp[ch][nq + 8];
      __syncthreads();   // vtmp/Bs reads done before next tile writes
    }
  }
}

// ---------------- K3: attention (block = (m,h), 8 waves x 32 queries) ------
__global__ __launch_bounds__(512, 4) void k_attn(const f16* __restrict__ q,
    const f16* __restrict__ k, const f16* __restrict__ vT, f16* __restrict__ o)
{
  __shared__ f16 ks[256][40];
  __shared__ f16 vt[32][264];
  int bx = blockIdx.x;
  int m = bx >> 3, h = bx & 7;
  int t = threadIdx.x, lane = t & 63, w = t >> 6;
  int i32 = lane & 31, hi = lane >> 5;
  size_t rowbase = (size_t)m * 256;
#pragma unroll
  for (int p = 0; p < 2; ++p) {
    int n = p * 128 + (t >> 2);
    int c0 = (t & 3) * 8;
    *(f16x8*)&ks[n][c0] = *(const f16x8*)(k + (rowbase + n) * 256 + h * 32 + c0);
  }
#pragma unroll
  for (int p = 0; p < 2; ++p) {
    int idx = p * 512 + t;
    int c = idx >> 5, nb = (idx & 31) * 8;
    *(f16x8*)&vt[c][nb] = *(const f16x8*)(vT + ((size_t)m * 256 + h * 32 + c) * 256 + nb);
  }
  __syncthreads();
  int qi0 = w * 32;
  const f16* qp = q + (rowbase + qi0 + i32) * 256 + h * 32 + hi * 8;
  f16x8 qf0 = *(const f16x8*)(qp);
  f16x8 qf1 = *(const f16x8*)(qp + 16);
  f32x16 O = {};
  float m_run = -1e30f, l_run = 0.f;
#pragma unroll 2
  for (int kb = 0; kb < 8; ++kb) {
    f16x8 kf0 = *(const f16x8*)&ks[kb * 32 + i32][hi * 8];
    f16x8 kf1 = *(const f16x8*)&ks[kb * 32 + i32][16 + hi * 8];
    f32x16 s = {};
    __builtin_amdgcn_s_setprio(1);
    s = __builtin_amdgcn_mfma_f32_32x32x16_f16(kf0, qf0, s, 0, 0, 0);
    s = __builtin_amdgcn_mfma_f32_32x32x16_f16(kf1, qf1, s, 0, 0, 0);
    __builtin_amdgcn_s_setprio(0);
#pragma unroll
    for (int r = 0; r < 16; ++r) s[r] *= L2E;
    float pmax = s[0];
#pragma unroll
    for (int r = 1; r < 16; ++r) pmax = fmaxf(pmax, s[r]);
    pmax = fmaxf(pmax, __shfl_xor(pmax, 32, 64));
    if (!__all(pmax - m_run <= 8.f)) {
      float m_new = fmaxf(m_run, pmax);
      float f = __builtin_amdgcn_exp2f(m_run - m_new);
      l_run *= f;
#pragma unroll
      for (int r = 0; r < 16; ++r)
        O[r] *= __shfl(f, (r & 3) + 8 * (r >> 2) + 4 * hi, 64);
      m_run = m_new;
    }
    float lsum = 0.f;
#pragma unroll
    for (int r = 0; r < 16; ++r) {
      float e = __builtin_amdgcn_exp2f(s[r] - m_run);
      s[r] = e;
      lsum += e;
    }
    lsum += __shfl_xor(lsum, 32, 64);
    l_run += lsum;
    int W0[4], W1[4];
#pragma unroll
    for (int qq = 0; qq < 4; ++qq) {
      W0[qq] = pk2(s[4 * qq],     s[4 * qq + 1]);
      W1[qq] = pk2(s[4 * qq + 2], s[4 * qq + 3]);
    }
#pragma unroll
    for (int ks2 = 0; ks2 < 2; ++ks2) {
      int X0 = W0[2 * ks2], Y0 = W0[2 * ks2 + 1];
      int X1 = W1[2 * ks2], Y1 = W1[2 * ks2 + 1];
      int a0 = __shfl(X0, i32, 64),      b0 = __shfl(Y0, i32, 64);
      int a1 = __shfl(X1, i32, 64),      b1 = __shfl(Y1, i32, 64);
      int a2 = __shfl(X0, i32 + 32, 64), b2 = __shfl(Y0, i32 + 32, 64);
      int a3 = __shfl(X1, i32 + 32, 64), b3 = __shfl(Y1, i32 + 32, 64);
      union { unsigned int ww[4]; f16x8 v; } pa;
      pa.ww[0] = hi ? (unsigned)b0 : (unsigned)a0;
      pa.ww[1] = hi ? (unsigned)b1 : (unsigned)a1;
      pa.ww[2] = hi ? (unsigned)b2 : (unsigned)a2;
      pa.ww[3] = hi ? (unsigned)b3 : (unsigned)a3;
      f16x8 vb = *(const f16x8*)&vt[i32][kb * 32 + ks2 * 16 + hi * 8];
      __builtin_amdgcn_s_setprio(1);
      O = __builtin_amdgcn_mfma_f32_32x32x16_f16(pa.v, vb, O, 0, 0, 0);
      __builtin_amdgcn_s_setprio(0);
    }
  }
  float inv = 1.f / l_run;
#pragma unroll
  for (int r = 0; r < 16; ++r) {
    int i = (r & 3) + 8 * (r >> 2) + 4 * hi;
    float fr = __shfl(inv, i, 64);
    o[(rowbase + (size_t)(qi0 + i)) * 256 + h * 32 + i32] = (f16)(O[r] * fr);
  }
}

// ---------------- K4: output projection — A in registers, B LDS-staged ----
// grid (512 row-tiles, 2 col-halves), 256 thr / 4 waves, wave = 16 rows.
__global__ __launch_bounds__(256, 4) void k_out(const f16* __restrict__ a,
    const f16* __restrict__ bw, const float* __restrict__ bias,
    float* __restrict__ out)
{
  __shared__ f16 Bs[64][264];
  int bm = blockIdx.x;
  int half = blockIdx.y;
  int t = threadIdx.x, lane = t & 63, w = t >> 6;
  int l15 = lane & 15, l4 = lane >> 4;
  int r0 = bm * 64 + w * 16;
  int pr = t >> 2, pc = (t & 3) * 8;
  f16x8 af[8];
#pragma unroll
  for (int kt = 0; kt < 8; ++kt)
    af[kt] = *(const f16x8*)(a + (size_t)(r0 + l15) * 256 + kt * 32 + l4 * 8);
  for (int ct = 0; ct < 2; ++ct) {
    int col0 = half * 128 + ct * 64;
#pragma unroll
    for (int p = 0; p < 8; ++p)
      *(f16x8*)&Bs[pr][pc + p * 32] =
        *(const f16x8*)(bw + (size_t)(col0 + pr) * 256 + pc + p * 32);
    __syncthreads();
    f32x4 acc[4] = {};
#pragma unroll
    for (int kt = 0; kt < 8; ++kt) {
#pragma unroll
      for (int ni = 0; ni < 4; ++ni) {
        f16x8 bf = *(const f16x8*)&Bs[ni * 16 + l15][kt * 32 + l4 * 8];
        acc[ni] = __builtin_amdgcn_mfma_f32_16x16x32_f16(af[kt], bf, acc[ni], 0, 0, 0);
      }
    }
#pragma unroll
    for (int ni = 0; ni < 4; ++ni) {
      float bv = bias[col0 + ni * 16 + l15];
#pragma unroll
      for (int r = 0; r < 4; ++r)
        out[(size_t)(r0 + l4 * 4 + r) * 256 + col0 + ni * 16 + l15] = acc[ni][r] + bv;
    }
    __syncthreads();
  }
}

extern "C" void kernel_launch(void* const* d_in, const int* in_sizes, int n_in,
                              void* d_out, int out_size, void* d_ws, size_t ws_size,
                              hipStream_t stream)
{
  const float* x  = (const float*)d_in[0];
  const float* g  = (const float*)d_in[1];
  const float* b  = (const float*)d_in[2];
  const float* wq = (const float*)d_in[3];
  const float* wk = (const float*)d_in[4];
  const float* wv = (const float*)d_in[5];
  const float* wf = (const float*)d_in[6];
  const float* bf = (const float*)d_in[7];
  float* out = (float*)d_out;

  char* ws = (char*)d_ws;
  f16* xh  = (f16*)(ws);                                 // LN output
  f16* qh  = (f16*)(ws + (size_t)16 * 1024 * 1024);
  f16* kh  = (f16*)(ws + (size_t)32 * 1024 * 1024);
  f16* vTh = (f16*)(ws + (size_t)48 * 1024 * 1024);      // [m][ch][n]
  char* wbase = ws + (size_t)64 * 1024 * 1024;
  f16* bq = (f16*)(wbase);
  f16* bk = (f16*)(wbase + 128 * 1024);
  f16* bv = (f16*)(wbase + 256 * 1024);
  f16* bw = (f16*)(wbase + 384 * 1024);
  f16* ah = (f16*)(ws + (size_t)80 * 1024 * 1024);       // attn output

  k_prep<<<16,           256, 0, stream>>>(wq, wk, wv, wf, bq, bk, bv, bw);
  k_ln  <<<ROWS / 4,     256, 0, stream>>>(x, g, b, xh);
  k_qkv <<<dim3(512, 3), 256, 0, stream>>>(xh, bq, bk, bv, qh, kh, vTh);
  k_attn<<<1024,         512, 0, stream>>>(qh, kh, vTh, ah);
  k_out <<<dim3(512, 2), 256, 0, stream>>>(ah, bw, bf, out);
}